// Round 1
// baseline (437.476 us; speedup 1.0000x reference)
//
#include <hip/hip_runtime.h>

// B=8, L=2048, H=1024. fp32 in/out, bf16 MFMA internally.
// Pipeline: convert -> GEMM<0> (QKV proj) -> transpose V -> GEMM<1> (P=exp(QK^T), diag=0)
//           -> row_sum (denom) -> GEMM<2> (out = P@V / denom)

typedef unsigned short u16;
typedef __bf16 bfx8 __attribute__((ext_vector_type(8)));
typedef float f32x4 __attribute__((ext_vector_type(4)));

__device__ __forceinline__ u16 f2bf(float f) {
    unsigned int x = __float_as_uint(f);
    unsigned int r = (x + 0x7fffu + ((x >> 16) & 1u)) >> 16;  // RNE
    return (u16)r;
}
__device__ __forceinline__ float bf2f(u16 u) {
    return __uint_as_float(((unsigned int)u) << 16);
}

// ---------------- fp32 -> bf16 convert (8 elems/thread) ----------------
__global__ void f32_to_bf16(const float* __restrict__ src, u16* __restrict__ dst, int n8) {
    int i = blockIdx.x * blockDim.x + threadIdx.x;
    if (i < n8) {
        float4 a = ((const float4*)src)[i * 2];
        float4 b = ((const float4*)src)[i * 2 + 1];
        ushort4 lo; lo.x = f2bf(a.x); lo.y = f2bf(a.y); lo.z = f2bf(a.z); lo.w = f2bf(a.w);
        ushort4 hi; hi.x = f2bf(b.x); hi.y = f2bf(b.y); hi.z = f2bf(b.z); hi.w = f2bf(b.w);
        ((ushort4*)dst)[i * 2] = lo;
        ((ushort4*)dst)[i * 2 + 1] = hi;
    }
}

// ---------------- bf16 transpose: [8][2048][1024] -> [8][1024][2048] ----------------
__global__ void transpose_bf16(const u16* __restrict__ src, u16* __restrict__ dst) {
    __shared__ u16 s[64][64 + 8];
    int z = blockIdx.z;
    int tm = blockIdx.x * 64;   // m tile
    int th = blockIdx.y * 64;   // h tile
    const u16* sp = src + (long)z * 2048 * 1024;
    u16* dp = dst + (long)z * 1024 * 2048;
    int t = threadIdx.x;
#pragma unroll
    for (int p = 0; p < 4; ++p) {
        int r = p * 16 + (t >> 4);
        int c = (t & 15) * 4;
        ushort4 v = *(const ushort4*)(sp + (long)(tm + r) * 1024 + th + c);
        s[r][c] = v.x; s[r][c + 1] = v.y; s[r][c + 2] = v.z; s[r][c + 3] = v.w;
    }
    __syncthreads();
#pragma unroll
    for (int p = 0; p < 4; ++p) {
        int hr = p * 16 + (t >> 4);
        int c = (t & 15) * 4;
        ushort4 v;
        v.x = s[c][hr]; v.y = s[c + 1][hr]; v.z = s[c + 2][hr]; v.w = s[c + 3][hr];
        *(ushort4*)(dp + (long)(th + hr) * 2048 + tm + c) = v;
    }
}

// ---------------- row sums of P (bf16, row length 2048) ----------------
__global__ void row_sum(const u16* __restrict__ P, float* __restrict__ denom) {
    int row = blockIdx.x;
    int t = threadIdx.x;  // 256
    const u16* p = P + (long)row * 2048 + t * 8;
    ushort4 a = *(const ushort4*)p;
    ushort4 b = *(const ushort4*)(p + 4);
    float s = bf2f(a.x) + bf2f(a.y) + bf2f(a.z) + bf2f(a.w)
            + bf2f(b.x) + bf2f(b.y) + bf2f(b.z) + bf2f(b.w);
#pragma unroll
    for (int off = 32; off >= 1; off >>= 1) s += __shfl_down(s, off);
    __shared__ float ws[4];
    if ((t & 63) == 0) ws[t >> 6] = s;
    __syncthreads();
    if (t == 0) denom[row] = ws[0] + ws[1] + ws[2] + ws[3];
}

// ---------------- NT GEMM: C[M,N] = A[M,K] @ B[N,K]^T (bf16 in, fp32 acc) ----------------
// MODE 0: epilogue += biasCat[col]; col<1024 scaled by 1/1024; store bf16 to qkv buffers.
// MODE 1: epilogue p = (row==col) ? 0 : exp(acc); store bf16 P.
// MODE 2: epilogue out = acc / denom[row]; store fp32.
#define BM 128
#define BN 128
#define BK 64

template <int MODE>
__global__ __launch_bounds__(256, 2) void gemm_nt(
    const u16* __restrict__ Ab, const u16* __restrict__ Bb,
    int K, int lda, int ldb,
    long strideA, long strideB,
    const float* __restrict__ biasCat,
    u16* __restrict__ outBf, long strideP,
    const float* __restrict__ denom,
    float* __restrict__ outF)
{
    __shared__ __align__(16) u16 sA[2][BM * BK];
    __shared__ __align__(16) u16 sB[2][BN * BK];
    const int tid  = threadIdx.x;
    const int lane = tid & 63;
    const int wid  = tid >> 6;
    const int wr = wid >> 1, wc = wid & 1;   // 2x2 wave grid, each wave: 64x64
    const int z = blockIdx.z;
    const u16* A = Ab + (long)z * strideA + (long)blockIdx.x * BM * lda;
    const u16* B = Bb + (long)z * strideB + (long)blockIdx.y * BN * ldb;
    const int ldab = lda * 2, ldbb = ldb * 2;

    f32x4 acc[4][4] = {};
    const int nt = K / BK;

    auto stage = [&](int buf, int t) {
        const char* ga = (const char*)A + (long)t * (BK * 2);
        const char* gb = (const char*)B + (long)t * (BK * 2);
#pragma unroll
        for (int i = 0; i < 4; ++i) {
            int c  = i * 256 + tid;
            int r  = c >> 3;               // row within tile (128 rows, 8x16B chunks/row)
            int lb = (c & 7) << 4;         // LDS byte-col within 128B row
            int sb = lb ^ ((r & 7) << 4);  // pre-swizzled global source byte-col
            {
                const char* g = ga + (long)r * ldab + sb;
                char* l = (char*)&sA[buf][0] + (wid << 10) + (i << 12);
                __builtin_amdgcn_global_load_lds((__attribute__((address_space(1))) void*)g,
                                                 (__attribute__((address_space(3))) void*)l, 16, 0, 0);
            }
            {
                const char* g = gb + (long)r * ldbb + sb;
                char* l = (char*)&sB[buf][0] + (wid << 10) + (i << 12);
                __builtin_amdgcn_global_load_lds((__attribute__((address_space(1))) void*)g,
                                                 (__attribute__((address_space(3))) void*)l, 16, 0, 0);
            }
        }
    };

    stage(0, 0);
    __syncthreads();
    int cur = 0;
    for (int t = 0; t < nt; ++t) {
        if (t + 1 < nt) stage(cur ^ 1, t + 1);
#pragma unroll
        for (int kk = 0; kk < 2; ++kk) {
            bfx8 av[4], bv[4];
#pragma unroll
            for (int mi = 0; mi < 4; ++mi) {
                int row = wr * 64 + mi * 16 + (lane & 15);
                int kb  = kk * 64 + ((lane >> 4) << 4);
                int off = row * 128 + (kb ^ ((row & 7) << 4));
                av[mi] = *(const bfx8*)((const char*)&sA[cur][0] + off);
            }
#pragma unroll
            for (int ni = 0; ni < 4; ++ni) {
                int row = wc * 64 + ni * 16 + (lane & 15);
                int kb  = kk * 64 + ((lane >> 4) << 4);
                int off = row * 128 + (kb ^ ((row & 7) << 4));
                bv[ni] = *(const bfx8*)((const char*)&sB[cur][0] + off);
            }
#pragma unroll
            for (int mi = 0; mi < 4; ++mi)
#pragma unroll
                for (int ni = 0; ni < 4; ++ni)
                    acc[mi][ni] = __builtin_amdgcn_mfma_f32_16x16x32_bf16(av[mi], bv[ni], acc[mi][ni], 0, 0, 0);
        }
        __syncthreads();
        cur ^= 1;
    }

    // epilogue: D row = (lane>>4)*4 + r, col = lane&15 within each 16x16 fragment
#pragma unroll
    for (int mi = 0; mi < 4; ++mi) {
#pragma unroll
        for (int ni = 0; ni < 4; ++ni) {
#pragma unroll
            for (int r = 0; r < 4; ++r) {
                int grow = blockIdx.x * BM + wr * 64 + mi * 16 + ((lane >> 4) << 2) + r;
                int gcol = blockIdx.y * BN + wc * 64 + ni * 16 + (lane & 15);
                float v = acc[mi][ni][r];
                if constexpr (MODE == 0) {
                    v += biasCat[gcol];
                    if (gcol < 1024) v *= (1.0f / 1024.0f);  // fold 1/hidden into q (exact pow2)
                    int which = gcol >> 10;
                    long dst = (long)which * (16384L * 1024) + (long)grow * 1024 + (gcol & 1023);
                    outBf[dst] = f2bf(v);
                } else if constexpr (MODE == 1) {
                    float p = (grow == gcol) ? 0.0f : __expf(v);  // no max-sub needed: |S|<~0.1
                    outBf[(long)z * strideP + (long)grow * 2048 + gcol] = f2bf(p);
                } else {
                    float d = denom[z * 2048 + grow];
                    outF[(long)z * (2048L * 1024) + (long)grow * 1024 + gcol] = v / d;
                }
            }
        }
    }
}

extern "C" void kernel_launch(void* const* d_in, const int* in_sizes, int n_in,
                              void* d_out, int out_size, void* d_ws, size_t ws_size,
                              hipStream_t stream) {
    const float* x  = (const float*)d_in[0];
    const float* Wq = (const float*)d_in[1];
    const float* bq = (const float*)d_in[2];
    const float* Wk = (const float*)d_in[3];
    const float* bk = (const float*)d_in[4];
    const float* Wv = (const float*)d_in[5];
    const float* bv = (const float*)d_in[6];
    float* out = (float*)d_out;

    // workspace layout (bytes); vT aliases dead xb, P overlays dead v
    const long XB_OFF   = 0;                         // xb: 33554432 ; later vT (same size)
    const long WB_OFF   = 33554432;                  // Wqkv bf16: 6291456
    const long BIAS_OFF = WB_OFF + 6291456;          // 12288
    const long DEN_OFF  = BIAS_OFF + 12288;          // 65536
    const long QKV_OFF  = DEN_OFF + 65536;           // q,k,v: 3 * 33554432
    const long PB_OFF   = QKV_OFF + 2L * 33554432;   // P overlays v: 67108864
    const unsigned long long NEED = (unsigned long long)(PB_OFF + 67108864);
    if (ws_size < NEED) return;  // refuse to corrupt; will show as absmax==ref-max

    char* ws = (char*)d_ws;
    u16*   xb      = (u16*)(ws + XB_OFF);
    u16*   vT      = (u16*)(ws + XB_OFF);
    u16*   Wb      = (u16*)(ws + WB_OFF);
    float* biasCat = (float*)(ws + BIAS_OFF);
    float* den     = (float*)(ws + DEN_OFF);
    u16*   qkv     = (u16*)(ws + QKV_OFF);
    u16*   qb = qkv;
    u16*   kb = qkv + 16384L * 1024;
    u16*   vb = qkv + 2L * 16384 * 1024;
    u16*   Pb = (u16*)(ws + PB_OFF);

    // converts
    f32_to_bf16<<<8192, 256, 0, stream>>>(x, xb, 2097152);
    f32_to_bf16<<<512, 256, 0, stream>>>(Wq, Wb, 131072);
    f32_to_bf16<<<512, 256, 0, stream>>>(Wk, Wb + 1048576, 131072);
    f32_to_bf16<<<512, 256, 0, stream>>>(Wv, Wb + 2097152, 131072);
    hipMemcpyAsync(biasCat,        bq, 4096, hipMemcpyDeviceToDevice, stream);
    hipMemcpyAsync(biasCat + 1024, bk, 4096, hipMemcpyDeviceToDevice, stream);
    hipMemcpyAsync(biasCat + 2048, bv, 4096, hipMemcpyDeviceToDevice, stream);

    // QKV projection: [16384,1024] @ [3072,1024]^T -> q,k,v (q pre-scaled 1/1024)
    gemm_nt<0><<<dim3(128, 24, 1), 256, 0, stream>>>(
        xb, Wb, 1024, 1024, 1024, 0, 0, biasCat, qkv, 0, nullptr, nullptr);

    // V transpose per batch: [2048,1024] -> [1024,2048]
    transpose_bf16<<<dim3(32, 16, 8), 256, 0, stream>>>(vb, vT);

    // P = exp(Q @ K^T), diag->0, bf16 ; per batch 2048x2048, K=1024
    gemm_nt<1><<<dim3(16, 16, 8), 256, 0, stream>>>(
        qb, kb, 1024, 1024, 1024, 2048L * 1024, 2048L * 1024,
        nullptr, Pb, 2048L * 2048, nullptr, nullptr);

    // denom = row sums of P
    row_sum<<<16384, 256, 0, stream>>>(Pb, den);

    // out = (P @ vT^T) / denom ; per batch 2048x1024, K=2048
    gemm_nt<2><<<dim3(16, 8, 8), 256, 0, stream>>>(
        Pb, vT, 2048, 2048, 2048, 2048L * 2048, 1024L * 2048,
        nullptr, nullptr, 0, den, out);
}

// Round 2
// 389.217 us; speedup vs baseline: 1.1240x; 1.1240x over previous
//
#include <hip/hip_runtime.h>

// B=8, L=2048, H=1024. fp32 in/out, bf16 MFMA internally.
// Pipeline: convert -> gemm8<0> (QKV proj) -> transpose V -> gemm8<1> (P=exp(QK^T), diag=0, fused row-sum)
//           -> gemm8<2> (out = P@V / denom)
// gemm8: 256x256 tile, BK=64, 8 waves (2x4), 8-phase schedule, counted vmcnt(4),
//        st-swizzled LDS via pre-swizzled global source, setprio around MFMA clusters.

typedef unsigned short u16;
typedef __bf16 bfx8 __attribute__((ext_vector_type(8)));
typedef float f32x4 __attribute__((ext_vector_type(4)));

__device__ __forceinline__ u16 f2bf(float f) {
    unsigned int x = __float_as_uint(f);
    unsigned int r = (x + 0x7fffu + ((x >> 16) & 1u)) >> 16;  // RNE
    return (u16)r;
}
__device__ __forceinline__ float bf2f(u16 u) {
    return __uint_as_float(((unsigned int)u) << 16);
}

// ---------------- fp32 -> bf16 convert (8 elems/thread) ----------------
__global__ void f32_to_bf16(const float* __restrict__ src, u16* __restrict__ dst, int n8) {
    int i = blockIdx.x * blockDim.x + threadIdx.x;
    if (i < n8) {
        float4 a = ((const float4*)src)[i * 2];
        float4 b = ((const float4*)src)[i * 2 + 1];
        ushort4 lo; lo.x = f2bf(a.x); lo.y = f2bf(a.y); lo.z = f2bf(a.z); lo.w = f2bf(a.w);
        ushort4 hi; hi.x = f2bf(b.x); hi.y = f2bf(b.y); hi.z = f2bf(b.z); hi.w = f2bf(b.w);
        ((ushort4*)dst)[i * 2] = lo;
        ((ushort4*)dst)[i * 2 + 1] = hi;
    }
}

// ---------------- bf16 transpose: [8][2048][1024] -> [8][1024][2048] ----------------
__global__ void transpose_bf16(const u16* __restrict__ src, u16* __restrict__ dst) {
    __shared__ u16 s[64][64 + 8];
    int z = blockIdx.z;
    int tm = blockIdx.x * 64;
    int th = blockIdx.y * 64;
    const u16* sp = src + (long)z * 2048 * 1024;
    u16* dp = dst + (long)z * 1024 * 2048;
    int t = threadIdx.x;
#pragma unroll
    for (int p = 0; p < 4; ++p) {
        int r = p * 16 + (t >> 4);
        int c = (t & 15) * 4;
        ushort4 v = *(const ushort4*)(sp + (long)(tm + r) * 1024 + th + c);
        s[r][c] = v.x; s[r][c + 1] = v.y; s[r][c + 2] = v.z; s[r][c + 3] = v.w;
    }
    __syncthreads();
#pragma unroll
    for (int p = 0; p < 4; ++p) {
        int hr = p * 16 + (t >> 4);
        int c = (t & 15) * 4;
        ushort4 v;
        v.x = s[c][hr]; v.y = s[c + 1][hr]; v.z = s[c + 2][hr]; v.w = s[c + 3][hr];
        *(ushort4*)(dp + (long)(th + hr) * 2048 + tm + c) = v;
    }
}

// ---------------- 256x256 8-phase NT GEMM ----------------
// C[M,N] = A[M,K] @ B[N,K]^T, bf16 in, fp32 acc.
// MODE 0: +biasCat[col]; col<1024 scaled 1/1024; store bf16 to q/k/v.
// MODE 1: p = (row==col)?0:exp(acc); store bf16 P; fused row-sum atomicAdd -> den.
// MODE 2: out = acc / den[row]; store fp32.

#define PH_MID() do{ asm volatile("" ::: "memory"); __builtin_amdgcn_s_barrier(); \
    asm volatile("s_waitcnt lgkmcnt(0)" ::: "memory"); __builtin_amdgcn_sched_barrier(0); \
    __builtin_amdgcn_s_setprio(1); }while(0)
#define PH_END() do{ __builtin_amdgcn_s_setprio(0); asm volatile("" ::: "memory"); \
    __builtin_amdgcn_s_barrier(); }while(0)

#define RD_A(cur, mibase) do{ \
    const char* _b = smem + (cur)*65536 + (wr*128 + (mibase)*16 + rA)*128; \
    a[0][0] = *(const bfx8*)(_b + 0*2048 + ofk0); a[0][1] = *(const bfx8*)(_b + 0*2048 + ofk1); \
    a[1][0] = *(const bfx8*)(_b + 1*2048 + ofk0); a[1][1] = *(const bfx8*)(_b + 1*2048 + ofk1); \
    a[2][0] = *(const bfx8*)(_b + 2*2048 + ofk0); a[2][1] = *(const bfx8*)(_b + 2*2048 + ofk1); \
    a[3][0] = *(const bfx8*)(_b + 3*2048 + ofk0); a[3][1] = *(const bfx8*)(_b + 3*2048 + ofk1); \
}while(0)

#define RD_B(cur, nibase) do{ \
    const char* _b = smem + (cur)*65536 + 32768 + (wc*64 + (nibase)*16 + rA)*128; \
    b[(nibase)+0][0] = *(const bfx8*)(_b + 0*2048 + ofk0); b[(nibase)+0][1] = *(const bfx8*)(_b + 0*2048 + ofk1); \
    b[(nibase)+1][0] = *(const bfx8*)(_b + 1*2048 + ofk0); b[(nibase)+1][1] = *(const bfx8*)(_b + 1*2048 + ofk1); \
}while(0)

#define MMQ(M0, N0) do{ \
    _Pragma("unroll") \
    for (int ks = 0; ks < 2; ++ks) \
    _Pragma("unroll") \
    for (int mi = 0; mi < 4; ++mi) \
    _Pragma("unroll") \
    for (int ni = 0; ni < 2; ++ni) \
        acc[(M0)+mi][(N0)+ni] = __builtin_amdgcn_mfma_f32_16x16x32_bf16(a[mi][ks], b[(N0)+ni][ks], acc[(M0)+mi][(N0)+ni], 0, 0, 0); \
}while(0)

template <int MODE>
__global__ __launch_bounds__(512, 2) void gemm8(
    const u16* __restrict__ Ab, const u16* __restrict__ Bb,
    int K, int lda, int ldb,
    long strideA, long strideB,
    const float* __restrict__ biasCat,
    u16* __restrict__ outBf, long strideP,
    float* __restrict__ den,
    float* __restrict__ outF)
{
    __shared__ __align__(16) char smem[131072];  // [2 buf][A 32KB | B 32KB]
    const int tid  = threadIdx.x;
    const int lane = tid & 63;
    const int wid  = tid >> 6;
    const int wr = wid >> 2, wc = wid & 3;   // 2x4 wave grid; wave tile 128x64
    const int z = blockIdx.z;
    const u16* A = Ab + (long)z * strideA + (long)blockIdx.x * 256 * lda;
    const u16* B = Bb + (long)z * strideB + (long)blockIdx.y * 256 * ldb;
    const int NT = K >> 6;

    const int rA  = lane & 15;
    const int cg  = lane >> 4;
    const int swz = rA & 7;
    const int ofk0 = ((cg)     ^ swz) << 4;
    const int ofk1 = ((cg | 4) ^ swz) << 4;

    f32x4 acc[8][4] = {};
    bfx8 a[4][2], b[4][2];

    auto stage = [&](int buf, int isB, int half, int t) {
        const u16* src = isB ? B : A;
        const int ld = isB ? ldb : lda;
#pragma unroll
        for (int rnd = 0; rnd < 2; ++rnd) {
            int c = rnd * 512 + tid;
            int row = half * 128 + (c >> 3);
            int slot = c & 7;
            const u16* g = src + (long)row * ld + t * 64 + ((slot ^ (row & 7)) << 3);
            char* l = (char*)smem + buf * 65536 + isB * 32768 + half * 16384 + rnd * 8192 + wid * 1024;
            __builtin_amdgcn_global_load_lds((__attribute__((address_space(1))) void*)g,
                                             (__attribute__((address_space(3))) void*)l, 16, 0, 0);
        }
    };

    // prologue: tile0 fully + B halves of tile1 (steady-state invariant)
    stage(0, 0, 0, 0); stage(0, 0, 1, 0); stage(0, 1, 0, 0); stage(0, 1, 1, 0);
    stage(1, 1, 0, 1); stage(1, 1, 1, 1);
    asm volatile("s_waitcnt vmcnt(4)" ::: "memory");
    __builtin_amdgcn_s_barrier();

    int cur = 0;
    for (int t = 0; t < NT; ++t) {
        const int nxt = cur ^ 1;
        // P1: read A-lo + B-lo ; stage A0(t+1) -> other buf
        RD_A(cur, 0); RD_B(cur, 0);
        if (t + 1 < NT) stage(nxt, 0, 0, t + 1);
        PH_MID(); MMQ(0, 0); PH_END();
        // P2: read B-hi ; stage A1(t+1)
        RD_B(cur, 2);
        if (t + 1 < NT) stage(nxt, 0, 1, t + 1);
        PH_MID(); MMQ(0, 2); PH_END();
        // P3: read A-hi ; stage B0(t+2) -> current buf (B reads ended at P2)
        RD_A(cur, 4);
        if (t + 2 < NT) stage(cur, 1, 0, t + 2);
        PH_MID(); MMQ(4, 2); PH_END();
        // P4: no reads ; stage B1(t+2) ; counted vmcnt once per K-tile
        if (t + 2 < NT) stage(cur, 1, 1, t + 2);
        asm volatile("s_waitcnt vmcnt(4)" ::: "memory");
        PH_MID(); MMQ(4, 0); PH_END();
        cur = nxt;
    }

    // epilogue: C frag row = cg*4 + r, col = rA within each 16x16
    const int r0 = blockIdx.x * 256 + wr * 128 + (cg << 2);
    const int c0 = blockIdx.y * 256 + wc * 64 + rA;
#pragma unroll
    for (int mi = 0; mi < 8; ++mi) {
#pragma unroll
        for (int r = 0; r < 4; ++r) {
            const int grow = r0 + mi * 16 + r;
            if constexpr (MODE == 0) {
#pragma unroll
                for (int ni = 0; ni < 4; ++ni) {
                    int gcol = c0 + ni * 16;
                    float v = acc[mi][ni][r] + biasCat[gcol];
                    if (gcol < 1024) v *= (1.0f / 1024.0f);  // fold 1/hidden into q (exact pow2)
                    int which = gcol >> 10;
                    long dst = (long)which * (16384L * 1024) + (long)grow * 1024 + (gcol & 1023);
                    outBf[dst] = f2bf(v);
                }
            } else if constexpr (MODE == 1) {
                float s = 0.0f;
#pragma unroll
                for (int ni = 0; ni < 4; ++ni) {
                    int gcol = c0 + ni * 16;
                    float p = (grow == gcol) ? 0.0f : __expf(acc[mi][ni][r]);  // |S| small: no max-sub
                    u16 pb = f2bf(p);
                    outBf[(long)z * strideP + (long)grow * 2048 + gcol] = pb;
                    s += bf2f(pb);  // denom from the SAME rounded values used in PV
                }
                s += __shfl_xor(s, 1); s += __shfl_xor(s, 2);
                s += __shfl_xor(s, 4); s += __shfl_xor(s, 8);
                if (rA == 0) atomicAdd(&den[z * 2048 + grow], s);
            } else {
                float d = den[z * 2048 + grow];
#pragma unroll
                for (int ni = 0; ni < 4; ++ni)
                    outF[(long)z * (2048L * 1024) + (long)grow * 1024 + (c0 + ni * 16)] = acc[mi][ni][r] / d;
            }
        }
    }
}

extern "C" void kernel_launch(void* const* d_in, const int* in_sizes, int n_in,
                              void* d_out, int out_size, void* d_ws, size_t ws_size,
                              hipStream_t stream) {
    const float* x  = (const float*)d_in[0];
    const float* Wq = (const float*)d_in[1];
    const float* bq = (const float*)d_in[2];
    const float* Wk = (const float*)d_in[3];
    const float* bk = (const float*)d_in[4];
    const float* Wv = (const float*)d_in[5];
    const float* bv = (const float*)d_in[6];
    float* out = (float*)d_out;

    // workspace layout (bytes); vT aliases dead xb, P overlays dead v
    const long XB_OFF   = 0;                         // xb: 33554432 ; later vT
    const long WB_OFF   = 33554432;                  // Wqkv bf16: 6291456
    const long BIAS_OFF = WB_OFF + 6291456;          // 12288
    const long DEN_OFF  = BIAS_OFF + 12288;          // 65536
    const long QKV_OFF  = DEN_OFF + 65536;           // q,k,v
    const long PB_OFF   = QKV_OFF + 2L * 33554432;   // P overlays v
    const unsigned long long NEED = (unsigned long long)(PB_OFF + 67108864);
    if (ws_size < NEED) return;

    char* ws = (char*)d_ws;
    u16*   xb      = (u16*)(ws + XB_OFF);
    u16*   vT      = (u16*)(ws + XB_OFF);
    u16*   Wb      = (u16*)(ws + WB_OFF);
    float* biasCat = (float*)(ws + BIAS_OFF);
    float* den     = (float*)(ws + DEN_OFF);
    u16*   qkv     = (u16*)(ws + QKV_OFF);
    u16*   qb = qkv;
    u16*   kb = qkv + 16384L * 1024;
    u16*   vb = qkv + 2L * 16384 * 1024;
    u16*   Pb = (u16*)(ws + PB_OFF);

    f32_to_bf16<<<8192, 256, 0, stream>>>(x, xb, 2097152);
    f32_to_bf16<<<512, 256, 0, stream>>>(Wq, Wb, 131072);
    f32_to_bf16<<<512, 256, 0, stream>>>(Wk, Wb + 1048576, 131072);
    f32_to_bf16<<<512, 256, 0, stream>>>(Wv, Wb + 2097152, 131072);
    hipMemcpyAsync(biasCat,        bq, 4096, hipMemcpyDeviceToDevice, stream);
    hipMemcpyAsync(biasCat + 1024, bk, 4096, hipMemcpyDeviceToDevice, stream);
    hipMemcpyAsync(biasCat + 2048, bv, 4096, hipMemcpyDeviceToDevice, stream);
    hipMemsetAsync(den, 0, 65536, stream);  // fused row-sum accumulates into this

    // QKV projection: [16384,1024] @ [3072,1024]^T
    gemm8<0><<<dim3(64, 12, 1), 512, 0, stream>>>(
        xb, Wb, 1024, 1024, 1024, 0, 0, biasCat, qkv, 0, nullptr, nullptr);

    // V transpose per batch
    transpose_bf16<<<dim3(32, 16, 8), 256, 0, stream>>>(vb, vT);

    // P = exp(Q @ K^T), diag->0, bf16, fused row sums
    gemm8<1><<<dim3(8, 8, 8), 512, 0, stream>>>(
        qb, kb, 1024, 1024, 1024, 2048L * 1024, 2048L * 1024,
        nullptr, Pb, 2048L * 2048, den, nullptr);

    // out = (P @ vT^T) / denom
    gemm8<2><<<dim3(8, 4, 8), 512, 0, stream>>>(
        Pb, vT, 2048, 2048, 2048, 2048L * 2048, 1024L * 2048,
        nullptr, nullptr, 0, den, out);
}